// Round 5
// baseline (1235.661 us; speedup 1.0000x reference)
//
#include <hip/hip_runtime.h>
#include <cstdio>

typedef unsigned short u16;
typedef __bf16 bf16x8 __attribute__((ext_vector_type(8)));
typedef float  floatx4 __attribute__((ext_vector_type(4)));

// ---------- scalar helpers ----------
__device__ __forceinline__ float bf2f(u16 u) {
  union { unsigned int i; float f; } v; v.i = ((unsigned int)u) << 16; return v.f;
}
__device__ __forceinline__ u16 f2bf(float f) {
  union { float f; unsigned int i; } v; v.f = f;
  unsigned int x = v.i;
  return (u16)((x + 0x7fffu + ((x >> 16) & 1u)) >> 16);   // RNE
}
__device__ __forceinline__ float sigmoidf_(float x) { return 1.f / (1.f + __expf(-x)); }
__device__ __forceinline__ float tanhf_(float x) {
  float ax = fabsf(x);
  float e = __expf(-2.f * ax);
  return copysignf((1.f - e) / (1.f + e), x);
}

// LDS swizzle: 16B chunks, chunk' = chunk ^ (row&15). rowlen16 = chunks per row.
__device__ __forceinline__ int swzk(int row, int c16, int rowlen16) {
  return row * (rowlen16 * 8) + ((c16 ^ (row & 15)) << 3);
}

// ---------- one MFMA pass: M=64 (full tile) x N=JT*16 per wave, K=KC*128 ----------
// A from LDS (64 rows, rowlen KC*16 chunks); B fragments straight from global (L2-hot).
// BT rows are always 256 k-elements wide (KC=1 reads only k<128).
template<int KC, int JT>
__device__ __forceinline__ void mm_pass(const u16* ldsA, const u16* __restrict__ BT,
                                        int nb, int l16, int quad,
                                        floatx4 (&acc)[4][JT])
{
#pragma unroll
  for (int i = 0; i < 4; i++)
#pragma unroll
    for (int j = 0; j < JT; j++) acc[i][j] = (floatx4){0.f, 0.f, 0.f, 0.f};
#pragma unroll
  for (int kc = 0; kc < KC; kc++)
#pragma unroll
    for (int ks = 0; ks < 4; ks++) {
      bf16x8 a[4], b[JT];
#pragma unroll
      for (int j = 0; j < JT; j++)
        b[j] = *reinterpret_cast<const bf16x8*>(
            BT + (size_t)(nb + j * 16 + l16) * 256 + kc * 128 + ks * 32 + quad * 8);
#pragma unroll
      for (int i = 0; i < 4; i++)
        a[i] = *reinterpret_cast<const bf16x8*>(
            &ldsA[swzk(i * 16 + l16, kc * 16 + ks * 4 + quad, KC * 16)]);
#pragma unroll
      for (int i = 0; i < 4; i++)
#pragma unroll
        for (int j = 0; j < JT; j++)
          acc[i][j] = __builtin_amdgcn_mfma_f32_16x16x32_bf16(a[i], b[j], acc[i][j], 0, 0, 0);
    }
}

// ---------- k_cell: fused i/u/o for one level's parents. M-tile = 64 rows ----------
// A row m (staged once): [ x = emb[sen[o0+m]] | h_sum over ratio children ]
// Wave w: iu pass at B_iu rows [w*64, w*64+64) -> cols [w*32, w*32+32), gates interleaved
// (j&1: 0=i,1=u; col-group gl=j>>1). Same lane owns i,u of a column -> c with no shuffles;
// tanh(c) kept in regs for the o pass (cols [w*32,+32), B_o rows w*32 + j*16).
// fcsum may alias h_out: same-lane read-before-write on identical (row,col).
template<int KC>
__global__ __launch_bounds__(256, 4) void k_cell(
    const int* __restrict__ sen, const float* __restrict__ emb,
    const u16* __restrict__ h_prev, const u16* __restrict__ Biu,
    const u16* __restrict__ Bo, const u16* fcsum,
    u16* __restrict__ c_out, u16* h_out,
    const float* __restrict__ b_ix, const float* __restrict__ b_ih,
    const float* __restrict__ b_ux, const float* __restrict__ b_uh,
    const float* __restrict__ b_ox, const float* __restrict__ b_oh,
    long o0, int ratio, int has_fc)
{
  __shared__ __align__(16) u16 ldsA[64 * KC * 128];   // 16 KB (KC=1) / 32 KB (KC=2)
  const int tid = threadIdx.x;
  const long m0 = (long)blockIdx.x * 64;
  const int r = tid >> 2;                // staging row 0..63
  const int cg = tid & 3;                // 4 threads per row

  // ---- stage A (full K), one barrier ----
  {
    const float* xsrc = emb + (size_t)sen[o0 + m0 + r] * 128;
#pragma unroll
    for (int i = 0; i < KC * 4; i++) {
      const int c16 = cg * (KC * 4) + i;
      u16* dst = &ldsA[swzk(r, c16, KC * 16)];
      if (c16 < 16) {                    // x part (fp32 gather + convert)
        const float* s = xsrc + c16 * 8;
        float4 v0 = *reinterpret_cast<const float4*>(s);
        float4 v1 = *reinterpret_cast<const float4*>(s + 4);
        u16 ov[8] = { f2bf(v0.x), f2bf(v0.y), f2bf(v0.z), f2bf(v0.w),
                      f2bf(v1.x), f2bf(v1.y), f2bf(v1.z), f2bf(v1.w) };
        *reinterpret_cast<uint4*>(dst) = *reinterpret_cast<const uint4*>(ov);
      } else {                           // h_sum over children
        const u16* hb = h_prev + (m0 + r) * (long)ratio * 128 + (c16 - 16) * 8;
        float s8[8] = {0.f, 0.f, 0.f, 0.f, 0.f, 0.f, 0.f, 0.f};
        for (int cr = 0; cr < ratio; cr++) {
          uint4 v = *reinterpret_cast<const uint4*>(hb + cr * 128);
          const u16* p = reinterpret_cast<const u16*>(&v);
#pragma unroll
          for (int e = 0; e < 8; e++) s8[e] += bf2f(p[e]);
        }
        u16 ov[8];
#pragma unroll
        for (int e = 0; e < 8; e++) ov[e] = f2bf(s8[e]);
        *reinterpret_cast<uint4*>(dst) = *reinterpret_cast<const uint4*>(ov);
      }
    }
  }
  __syncthreads();

  const int lane = tid & 63, w = tid >> 6;
  const int l16 = lane & 15, quad = lane >> 4;

  // ---- i/u pass (one pass, 4 j-tiles) ----
  floatx4 acc[4][4];
  mm_pass<KC, 4>(ldsA, Biu, w * 64, l16, quad, acc);

  float tch[4][2][4];   // tanh(c) per [i][gl][r2]
#pragma unroll
  for (int gl = 0; gl < 2; gl++) {
    const int col = w * 32 + gl * 16 + l16;
    const float bi = b_ix[col] + b_ih[col];
    const float bu = b_ux[col] + b_uh[col];
#pragma unroll
    for (int i = 0; i < 4; i++)
#pragma unroll
      for (int r2 = 0; r2 < 4; r2++) {
        const long row = m0 + i * 16 + quad * 4 + r2;
        float cv = sigmoidf_(acc[i][2 * gl][r2] + bi) * tanhf_(acc[i][2 * gl + 1][r2] + bu);
        if (has_fc) cv += bf2f(fcsum[row * 128 + col]);
        c_out[row * 128 + col] = f2bf(cv);
        tch[i][gl][r2] = tanhf_(cv);
      }
  }

  // ---- o pass ----
  floatx4 acco[4][2];
  mm_pass<KC, 2>(ldsA, Bo, w * 32, l16, quad, acco);
#pragma unroll
  for (int j = 0; j < 2; j++) {
    const int col = w * 32 + j * 16 + l16;
    const float bo = b_ox[col] + b_oh[col];
#pragma unroll
    for (int i = 0; i < 4; i++)
#pragma unroll
      for (int r2 = 0; r2 < 4; r2++) {
        const long row = m0 + i * 16 + quad * 4 + r2;
        h_out[row * 128 + col] = f2bf(sigmoidf_(acco[i][j][r2] + bo) * tch[i][j][r2]);
      }
  }
}

// ---------- k_fc: f-gate over children; group-sums f*c into fcsum[parent]. M-tile = 64 ----------
// A row m: [ h_child[m] | x_parent = emb[sen[o0 + (m>>lr)]] ]
__global__ __launch_bounds__(256, 4) void k_fc(
    const int* __restrict__ sen, const float* __restrict__ emb,
    const u16* __restrict__ h_prev, const u16* __restrict__ Bf,
    const u16* __restrict__ c_prev, u16* __restrict__ fcsum,
    const float* __restrict__ b_fh, const float* __restrict__ b_fx,
    long o0, int lr)
{
  __shared__ __align__(16) u16 ldsA[64 * 256];   // 32 KB
  const int tid = threadIdx.x;
  const long m0 = (long)blockIdx.x * 64;
  const int r = tid >> 2, cg = tid & 3;

  {
    const u16* hsrc = h_prev + (m0 + r) * 128;
    const float* xsrc = emb + (size_t)sen[o0 + ((m0 + r) >> lr)] * 128;
#pragma unroll
    for (int i = 0; i < 8; i++) {
      const int c16 = cg * 8 + i;
      u16* dst = &ldsA[swzk(r, c16, 32)];
      if (c16 < 16) {
        *reinterpret_cast<uint4*>(dst) = *reinterpret_cast<const uint4*>(hsrc + c16 * 8);
      } else {
        const float* s = xsrc + (c16 - 16) * 8;
        float4 v0 = *reinterpret_cast<const float4*>(s);
        float4 v1 = *reinterpret_cast<const float4*>(s + 4);
        u16 ov[8] = { f2bf(v0.x), f2bf(v0.y), f2bf(v0.z), f2bf(v0.w),
                      f2bf(v1.x), f2bf(v1.y), f2bf(v1.z), f2bf(v1.w) };
        *reinterpret_cast<uint4*>(dst) = *reinterpret_cast<const uint4*>(ov);
      }
    }
  }
  __syncthreads();

  const int lane = tid & 63, w = tid >> 6;
  const int l16 = lane & 15, quad = lane >> 4;

  floatx4 acc[4][2];
  mm_pass<2, 2>(ldsA, Bf, w * 32, l16, quad, acc);

#pragma unroll
  for (int i = 0; i < 4; i++) {
    const long base = m0 + i * 16 + quad * 4;   // multiple of 4
#pragma unroll
    for (int j = 0; j < 2; j++) {
      const int jc = w * 32 + j * 16 + l16;
      const float bb = b_fh[jc] + b_fx[jc];
      float fcv[4];
#pragma unroll
      for (int r2 = 0; r2 < 4; r2++) {
        const float f = sigmoidf_(acc[i][j][r2] + bb);
        fcv[r2] = f * bf2f(c_prev[(base + r2) * 128 + jc]);
      }
      if (lr == 2) {
        fcsum[(base >> 2) * 128 + jc] = f2bf(fcv[0] + fcv[1] + fcv[2] + fcv[3]);
      } else if (lr == 1) {
        fcsum[(base >> 1) * 128 + jc]       = f2bf(fcv[0] + fcv[1]);
        fcsum[((base >> 1) + 1) * 128 + jc] = f2bf(fcv[2] + fcv[3]);
      } else {
#pragma unroll
        for (int r2 = 0; r2 < 4; r2++)
          fcsum[(base + r2) * 128 + jc] = f2bf(fcv[r2]);
      }
    }
  }
}

// ---------- weight prep ----------
// B_iu [256 n'][256 k]: n' = w*64 + j*16 + l -> gate = j&1, col = w*32 + (j>>1)*16 + l.
__global__ void build_biu(const float* __restrict__ Wix, const float* __restrict__ Wih,
                          const float* __restrict__ Wux, const float* __restrict__ Wuh,
                          u16* __restrict__ BT)
{
  int idx = blockIdx.x * 256 + threadIdx.x;   // 256*256
  int np = idx >> 8, k = idx & 255;
  int w = np >> 6, j = (np >> 4) & 3, l = np & 15;
  int gate = j & 1;
  int col = w * 32 + (j >> 1) * 16 + l;
  float v = (k < 128) ? (gate ? Wux[k * 128 + col] : Wix[k * 128 + col])
                      : (gate ? Wuh[(k - 128) * 128 + col] : Wih[(k - 128) * 128 + col]);
  BT[idx] = f2bf(v);
}

__global__ void build_bo(const float* __restrict__ Wox, const float* __restrict__ Woh,
                         u16* __restrict__ BT)
{
  int idx = blockIdx.x * 256 + threadIdx.x;   // 128*256
  int n = idx >> 8, k = idx & 255;
  float v = (k < 128) ? Wox[k * 128 + n] : Woh[(k - 128) * 128 + n];
  BT[idx] = f2bf(v);
}

__global__ void build_bf(const float* __restrict__ Wfh, const float* __restrict__ Wfx,
                         u16* __restrict__ BT)
{
  int idx = blockIdx.x * 256 + threadIdx.x;   // 128*256
  int n = idx >> 8, k = idx & 255;
  float v = (k < 128) ? Wfh[k * 128 + n] : Wfx[(k - 128) * 128 + n];
  BT[idx] = f2bf(v);
}

// ---------- output projection (4096 x 4, tiny) ----------
__global__ void out_proj(const u16* __restrict__ h_root, const float* __restrict__ W_out,
                         const float* __restrict__ b_out, float* __restrict__ out)
{
  int idx = blockIdx.x * 256 + threadIdx.x;   // 4096*4
  int n = idx >> 2, cls = idx & 3;
  float s = b_out[cls];
  for (int k = 0; k < 128; k++)
    s += bf2f(h_root[(long)n * 128 + k]) * W_out[k * 4 + cls];
  out[idx] = s;
}

extern "C" void kernel_launch(void* const* d_in, const int* in_sizes, int n_in,
                              void* d_out, int out_size, void* d_ws, size_t ws_size,
                              hipStream_t stream)
{
  const int*   sen  = (const int*)d_in[0];
  const float* emb  = (const float*)d_in[1];
  const float* W_ix = (const float*)d_in[2];  const float* b_ix = (const float*)d_in[3];
  const float* W_ih = (const float*)d_in[4];  const float* b_ih = (const float*)d_in[5];
  const float* W_fx = (const float*)d_in[6];  const float* b_fx = (const float*)d_in[7];
  const float* W_fh = (const float*)d_in[8];  const float* b_fh = (const float*)d_in[9];
  const float* W_ox = (const float*)d_in[10]; const float* b_ox = (const float*)d_in[11];
  const float* W_oh = (const float*)d_in[12]; const float* b_oh = (const float*)d_in[13];
  const float* W_ux = (const float*)d_in[14]; const float* b_ux = (const float*)d_in[15];
  const float* W_uh = (const float*)d_in[16]; const float* b_uh = (const float*)d_in[17];
  const float* W_out= (const float*)d_in[18]; const float* b_out= (const float*)d_in[19];
  float* out = (float*)d_out;

  // ---- workspace: 3 rotating 67.1 MB buffers + weights (~201.6 MB) ----
  const size_t SLOT = (size_t)262144 * 128 * 2;
  const size_t need = 3 * SLOT + ((size_t)256 * 256 + 2 * (size_t)128 * 256) * 2 + 4096;
  fprintf(stderr, "[tree_lstm] ws_size=%zu need=%zu\n", ws_size, need);
  if (ws_size < need) {
    fprintf(stderr, "[tree_lstm] INSUFFICIENT WORKSPACE — skipping launch\n");
    return;
  }
  char* ws = (char*)d_ws;
  size_t off = 0;
  auto take = [&](size_t bytes) { char* p = ws + off; off += (bytes + 255) & ~(size_t)255; return p; };
  u16* X   = (u16*)take(SLOT);   // h_prev / h_cur (rotates with Y)
  u16* Bc  = (u16*)take(SLOT);   // c (prev consumed by k_fc before k_cell overwrites)
  u16* Y   = (u16*)take(SLOT);   // fcsum then h_cur (rotates with X)
  u16* Biu = (u16*)take((size_t)256 * 256 * 2);
  u16* Bo  = (u16*)take((size_t)128 * 256 * 2);
  u16* Bf  = (u16*)take((size_t)128 * 256 * 2);

  build_biu<<<256, 256, 0, stream>>>(W_ix, W_ih, W_ux, W_uh, Biu);
  build_bo<<<128, 256, 0, stream>>>(W_ox, W_oh, Bo);
  build_bf<<<128, 256, 0, stream>>>(W_fh, W_fx, Bf);

  const long LOFF[6] = {0, 4096, 20480, 86016, 217088, 479232};
  const int  LSZ[6]  = {4096, 16384, 65536, 131072, 262144, 262144};
  const int  LLR[5]  = {2, 2, 1, 1, 0};   // log2(children per node), L=0..4

  // ---- leaf level L=5: K=128, h_sum=0, no f-path. c->Bc, h->Y ----
  k_cell<1><<<LSZ[5] / 64, 256, 0, stream>>>(sen, emb, X, Biu, Bo,
      nullptr, Bc, Y, b_ix, b_ih, b_ux, b_uh, b_ox, b_oh, LOFF[5], 1, 0);
  { u16* t = X; X = Y; Y = t; }

  // ---- levels 4..0: k_fc (children) then fused k_cell (parents); swap ----
  for (int L = 4; L >= 0; L--) {
    const long o0 = LOFF[L];
    const int nL = LSZ[L], nC = LSZ[L + 1];
    const int lr = LLR[L], ratio = 1 << lr;
    k_fc<<<nC / 64, 256, 0, stream>>>(sen, emb, X, Bf, Bc, Y, b_fh, b_fx, o0, lr);
    k_cell<2><<<nL / 64, 256, 0, stream>>>(sen, emb, X, Biu, Bo,
        Y, Bc, Y, b_ix, b_ih, b_ux, b_uh, b_ox, b_oh, o0, ratio, 1);
    u16* t = X; X = Y; Y = t;
  }

  out_proj<<<64, 256, 0, stream>>>(X, W_out, b_out, out);
}

// Round 6
// 913.333 us; speedup vs baseline: 1.3529x; 1.3529x over previous
//
#include <hip/hip_runtime.h>
#include <cstdio>

typedef unsigned short u16;
typedef __bf16 bf16x8 __attribute__((ext_vector_type(8)));
typedef float  floatx4 __attribute__((ext_vector_type(4)));

// ---------- scalar helpers ----------
__device__ __forceinline__ float bf2f(u16 u) {
  union { unsigned int i; float f; } v; v.i = ((unsigned int)u) << 16; return v.f;
}
__device__ __forceinline__ u16 f2bf(float f) {
  union { float f; unsigned int i; } v; v.f = f;
  unsigned int x = v.i;
  return (u16)((x + 0x7fffu + ((x >> 16) & 1u)) >> 16);   // RNE
}
__device__ __forceinline__ float sigmoidf_(float x) { return 1.f / (1.f + __expf(-x)); }
__device__ __forceinline__ float tanhf_(float x) {
  float ax = fabsf(x);
  float e = __expf(-2.f * ax);
  return copysignf((1.f - e) / (1.f + e), x);
}

// LDS swizzle for K=128 rows (16 chunks of 16B): chunk' = chunk ^ (row&15)
__device__ __forceinline__ int swz128(int row, int c16) {
  return row * 128 + ((c16 ^ (row & 15)) << 3);
}

// ============ proj_e: E'[v][512] = emb[v] @ [Wix|Wux|Wox|Wfx] + bias (bf16) ============
// grid (391, 4); block 256. Rows clamped at 49999 for loads; stores guarded.
__global__ __launch_bounds__(256) void proj_e(
    const float* __restrict__ emb, const u16* __restrict__ WT,
    const float* __restrict__ bsum, u16* __restrict__ Ep)
{
  __shared__ __align__(16) u16 ldsA[128 * 128];
  const int tid = threadIdx.x;
  const long m0 = (long)blockIdx.x * 128;
  const int n0 = blockIdx.y * 128;
  {
    const int r = tid >> 1, half = tid & 1;
    long row = m0 + r; if (row > 49999) row = 49999;
    const float* src = emb + row * 128 + half * 64;
#pragma unroll
    for (int i = 0; i < 8; i++) {
      float4 v0 = *reinterpret_cast<const float4*>(src + i * 8);
      float4 v1 = *reinterpret_cast<const float4*>(src + i * 8 + 4);
      u16 ov[8] = { f2bf(v0.x), f2bf(v0.y), f2bf(v0.z), f2bf(v0.w),
                    f2bf(v1.x), f2bf(v1.y), f2bf(v1.z), f2bf(v1.w) };
      *reinterpret_cast<uint4*>(&ldsA[swz128(r, half * 8 + i)]) =
          *reinterpret_cast<const uint4*>(ov);
    }
  }
  __syncthreads();
  const int lane = tid & 63, w = tid >> 6, l16 = lane & 15, quad = lane >> 4;
#pragma unroll
  for (int gl = 0; gl < 2; gl++) {
    const int col = n0 + w * 32 + gl * 16 + l16;
    bf16x8 b[4];
#pragma unroll
    for (int ks = 0; ks < 4; ks++)
      b[ks] = *reinterpret_cast<const bf16x8*>(WT + (size_t)col * 128 + ks * 32 + quad * 8);
    floatx4 acc[8];
#pragma unroll
    for (int i = 0; i < 8; i++) acc[i] = (floatx4){0.f, 0.f, 0.f, 0.f};
#pragma unroll
    for (int ks = 0; ks < 4; ks++)
#pragma unroll
      for (int i = 0; i < 8; i++) {
        bf16x8 a = *reinterpret_cast<const bf16x8*>(&ldsA[swz128(i * 16 + l16, ks * 4 + quad)]);
        acc[i] = __builtin_amdgcn_mfma_f32_16x16x32_bf16(a, b[ks], acc[i], 0, 0, 0);
      }
    const float bb = bsum[col];
#pragma unroll
    for (int i = 0; i < 8; i++)
#pragma unroll
      for (int r2 = 0; r2 < 4; r2++) {
        const long row = m0 + i * 16 + quad * 4 + r2;
        if (row < 50000) Ep[row * 512 + col] = f2bf(acc[i][r2] + bb);
      }
  }
}

// ============ k_leaf: c=sig(E'i)tanh(E'u); h=sig(E'o)tanh(c) — no GEMM ============
__global__ __launch_bounds__(256) void k_leaf(
    const int* __restrict__ sen, const u16* __restrict__ Ep,
    u16* __restrict__ c_out, u16* __restrict__ h_out, long o0)
{
  const int tid = threadIdx.x;
  const long node = (long)blockIdx.x * 128 + (tid >> 1);
  const int sec = (tid & 1) * 64;
  const u16* e = Ep + (size_t)sen[o0 + node] * 512 + sec;
  u16* cp = c_out + node * 128 + sec;
  u16* hp = h_out + node * 128 + sec;
#pragma unroll
  for (int ch = 0; ch < 8; ch++) {
    uint4 vi = *reinterpret_cast<const uint4*>(e + ch * 8);
    uint4 vu = *reinterpret_cast<const uint4*>(e + 128 + ch * 8);
    uint4 vo = *reinterpret_cast<const uint4*>(e + 256 + ch * 8);
    const u16* pi = reinterpret_cast<const u16*>(&vi);
    const u16* pu = reinterpret_cast<const u16*>(&vu);
    const u16* po = reinterpret_cast<const u16*>(&vo);
    u16 oc[8], oh[8];
#pragma unroll
    for (int k = 0; k < 8; k++) {
      float cv = sigmoidf_(bf2f(pi[k])) * tanhf_(bf2f(pu[k]));
      oc[k] = f2bf(cv);
      oh[k] = f2bf(sigmoidf_(bf2f(po[k])) * tanhf_(cv));
    }
    *reinterpret_cast<uint4*>(cp + ch * 8) = *reinterpret_cast<const uint4*>(oc);
    *reinterpret_cast<uint4*>(hp + ch * 8) = *reinterpret_cast<const uint4*>(oh);
  }
}

// ============ k_fc: f = sig(h_child@Wfh + E'f[parent]); fcsum = groupsum(f*c_child) ============
// M-tile = 64 children; block 256 (4 waves); wave w -> cols [w*32,+32), B in registers.
__global__ __launch_bounds__(256, 3) void k_fc(
    const int* __restrict__ sen, const u16* __restrict__ Ep,
    const u16* __restrict__ h_prev, const u16* __restrict__ c_prev,
    const u16* __restrict__ BfT, u16* __restrict__ fcsum, long o0, int lr)
{
  __shared__ __align__(16) u16 lds_hs[64 * 128];   // A (swizzled)
  __shared__ __align__(16) u16 lds_c[64 * 128];    // c_child (linear)
  __shared__ __align__(16) u16 lds_fc[64 * 128];   // fc output staging (linear)
  __shared__ int lds_sp[64];
  const int tid = threadIdx.x;
  const long m0 = (long)blockIdx.x * 64;
  {
    const int r = tid >> 2, q = tid & 3;
    const u16* hsrc = h_prev + (m0 + r) * 128 + q * 32;
#pragma unroll
    for (int i = 0; i < 4; i++)
      *reinterpret_cast<uint4*>(&lds_hs[swz128(r, q * 4 + i)]) =
          *reinterpret_cast<const uint4*>(hsrc + i * 8);
    const u16* csrc = c_prev + m0 * 128 + tid * 32;
#pragma unroll
    for (int i = 0; i < 4; i++)
      *reinterpret_cast<uint4*>(&lds_c[tid * 32 + i * 8]) =
          *reinterpret_cast<const uint4*>(csrc + i * 8);
    if (tid < (64 >> lr)) lds_sp[tid] = sen[o0 + (m0 >> lr) + tid];
  }
  __syncthreads();
  const int lane = tid & 63, w = tid >> 6, l16 = lane & 15, quad = lane >> 4;
#pragma unroll
  for (int gl = 0; gl < 2; gl++) {
    const int col = w * 32 + gl * 16 + l16;
    bf16x8 b[4];
#pragma unroll
    for (int ks = 0; ks < 4; ks++)
      b[ks] = *reinterpret_cast<const bf16x8*>(BfT + (size_t)col * 128 + ks * 32 + quad * 8);
    floatx4 acc[4];
#pragma unroll
    for (int i = 0; i < 4; i++) acc[i] = (floatx4){0.f, 0.f, 0.f, 0.f};
#pragma unroll
    for (int ks = 0; ks < 4; ks++)
#pragma unroll
      for (int i = 0; i < 4; i++) {
        bf16x8 a = *reinterpret_cast<const bf16x8*>(&lds_hs[swz128(i * 16 + l16, ks * 4 + quad)]);
        acc[i] = __builtin_amdgcn_mfma_f32_16x16x32_bf16(a, b[ks], acc[i], 0, 0, 0);
      }
#pragma unroll
    for (int i = 0; i < 4; i++) {
      const int rbase = i * 16 + quad * 4;
      float fcv[4];
#pragma unroll
      for (int r2 = 0; r2 < 4; r2++) {
        const int rl = rbase + r2;
        const float pre = acc[i][r2] + bf2f(Ep[(size_t)lds_sp[rl >> lr] * 512 + 384 + col]);
        fcv[r2] = sigmoidf_(pre) * bf2f(lds_c[rl * 128 + col]);
      }
      if (lr == 2) {
        lds_fc[(rbase >> 2) * 128 + col] = f2bf(fcv[0] + fcv[1] + fcv[2] + fcv[3]);
      } else if (lr == 1) {
        lds_fc[(rbase >> 1) * 128 + col]       = f2bf(fcv[0] + fcv[1]);
        lds_fc[((rbase >> 1) + 1) * 128 + col] = f2bf(fcv[2] + fcv[3]);
      } else {
#pragma unroll
        for (int r2 = 0; r2 < 4; r2++)
          lds_fc[(rbase + r2) * 128 + col] = f2bf(fcv[r2]);
      }
    }
  }
  __syncthreads();
  // dense store: (64>>lr) rows x 256 B, block-linear
  u16* dst = fcsum + (m0 >> lr) * 128;
  const int n16 = (64 >> lr) * 16;   // uint4 chunks
  for (int c = tid; c < n16; c += 256)
    *reinterpret_cast<uint4*>(dst + c * 8) = *reinterpret_cast<const uint4*>(&lds_fc[c * 8]);
}

// ============ k_cell: i/u/o from hsum (K=128, B in regs) + E' gather epilogue ============
// M-tile = 64 parents; block 256; wave w -> cols [w*32,+32).
__global__ __launch_bounds__(256, 2) void k_cell(
    const int* __restrict__ sen, const u16* __restrict__ Ep,
    const u16* __restrict__ h_prev,
    const u16* __restrict__ BihT, const u16* __restrict__ BuhT, const u16* __restrict__ BohT,
    const u16* __restrict__ fcsum, u16* __restrict__ c_out, u16* __restrict__ h_out,
    long o0, int ratio)
{
  __shared__ __align__(16) u16 lds_hs[64 * 128];   // A swizzled; reused for c transpose
  __shared__ __align__(16) u16 lds_fc[64 * 128];   // fcsum linear; reused for h transpose
  __shared__ int lds_s[64];
  const int tid = threadIdx.x;
  const long m0 = (long)blockIdx.x * 64;
  {
    const int r = tid >> 2, q = tid & 3;
    if (ratio == 1) {
      const u16* hsrc = h_prev + (m0 + r) * 128 + q * 32;
#pragma unroll
      for (int i = 0; i < 4; i++)
        *reinterpret_cast<uint4*>(&lds_hs[swz128(r, q * 4 + i)]) =
            *reinterpret_cast<const uint4*>(hsrc + i * 8);
    } else {
      const u16* hb = h_prev + (m0 + r) * (long)ratio * 128 + q * 32;
#pragma unroll
      for (int i = 0; i < 4; i++) {
        float s8[8] = {0.f, 0.f, 0.f, 0.f, 0.f, 0.f, 0.f, 0.f};
        for (int cr = 0; cr < ratio; cr++) {
          uint4 v = *reinterpret_cast<const uint4*>(hb + cr * 128 + i * 8);
          const u16* p = reinterpret_cast<const u16*>(&v);
#pragma unroll
          for (int e = 0; e < 8; e++) s8[e] += bf2f(p[e]);
        }
        u16 ov[8];
#pragma unroll
        for (int e = 0; e < 8; e++) ov[e] = f2bf(s8[e]);
        *reinterpret_cast<uint4*>(&lds_hs[swz128(r, q * 4 + i)]) =
            *reinterpret_cast<const uint4*>(ov);
      }
    }
    const u16* fsrc = fcsum + m0 * 128 + tid * 32;
#pragma unroll
    for (int i = 0; i < 4; i++)
      *reinterpret_cast<uint4*>(&lds_fc[tid * 32 + i * 8]) =
          *reinterpret_cast<const uint4*>(fsrc + i * 8);
    if (tid < 64) lds_s[tid] = sen[o0 + m0 + tid];
  }
  __syncthreads();
  const int lane = tid & 63, w = tid >> 6, l16 = lane & 15, quad = lane >> 4;

  float cv[2][4][4];
  // ---- i/u sub-passes ----
#pragma unroll
  for (int gl = 0; gl < 2; gl++) {
    const int col = w * 32 + gl * 16 + l16;
    bf16x8 bi[4], bu[4];
#pragma unroll
    for (int ks = 0; ks < 4; ks++) {
      bi[ks] = *reinterpret_cast<const bf16x8*>(BihT + (size_t)col * 128 + ks * 32 + quad * 8);
      bu[ks] = *reinterpret_cast<const bf16x8*>(BuhT + (size_t)col * 128 + ks * 32 + quad * 8);
    }
    floatx4 aI[4], aU[4];
#pragma unroll
    for (int i = 0; i < 4; i++) { aI[i] = (floatx4){0.f,0.f,0.f,0.f}; aU[i] = (floatx4){0.f,0.f,0.f,0.f}; }
#pragma unroll
    for (int ks = 0; ks < 4; ks++)
#pragma unroll
      for (int i = 0; i < 4; i++) {
        bf16x8 a = *reinterpret_cast<const bf16x8*>(&lds_hs[swz128(i * 16 + l16, ks * 4 + quad)]);
        aI[i] = __builtin_amdgcn_mfma_f32_16x16x32_bf16(a, bi[ks], aI[i], 0, 0, 0);
        aU[i] = __builtin_amdgcn_mfma_f32_16x16x32_bf16(a, bu[ks], aU[i], 0, 0, 0);
      }
#pragma unroll
    for (int i = 0; i < 4; i++)
#pragma unroll
      for (int r2 = 0; r2 < 4; r2++) {
        const int rl = i * 16 + quad * 4 + r2;
        const size_t eb = (size_t)lds_s[rl] * 512;
        const float preI = aI[i][r2] + bf2f(Ep[eb + col]);
        const float preU = aU[i][r2] + bf2f(Ep[eb + 128 + col]);
        cv[gl][i][r2] = sigmoidf_(preI) * tanhf_(preU) + bf2f(lds_fc[rl * 128 + col]);
      }
  }
  // ---- o pass (both col-groups in one K-loop) ----
  bf16x8 bo[2][4];
#pragma unroll
  for (int gl = 0; gl < 2; gl++)
#pragma unroll
    for (int ks = 0; ks < 4; ks++)
      bo[gl][ks] = *reinterpret_cast<const bf16x8*>(
          BohT + (size_t)(w * 32 + gl * 16 + l16) * 128 + ks * 32 + quad * 8);
  floatx4 aO[2][4];
#pragma unroll
  for (int gl = 0; gl < 2; gl++)
#pragma unroll
    for (int i = 0; i < 4; i++) aO[gl][i] = (floatx4){0.f, 0.f, 0.f, 0.f};
#pragma unroll
  for (int ks = 0; ks < 4; ks++)
#pragma unroll
    for (int i = 0; i < 4; i++) {
      bf16x8 a = *reinterpret_cast<const bf16x8*>(&lds_hs[swz128(i * 16 + l16, ks * 4 + quad)]);
#pragma unroll
      for (int gl = 0; gl < 2; gl++)
        aO[gl][i] = __builtin_amdgcn_mfma_f32_16x16x32_bf16(a, bo[gl][ks], aO[gl][i], 0, 0, 0);
    }
  __syncthreads();   // lds_hs / lds_fc dead — reuse for transpose
#pragma unroll
  for (int gl = 0; gl < 2; gl++) {
    const int col = w * 32 + gl * 16 + l16;
#pragma unroll
    for (int i = 0; i < 4; i++)
#pragma unroll
      for (int r2 = 0; r2 < 4; r2++) {
        const int rl = i * 16 + quad * 4 + r2;
        const size_t eb = (size_t)lds_s[rl] * 512;
        const float cc = cv[gl][i][r2];
        const float hh = sigmoidf_(aO[gl][i][r2] + bf2f(Ep[eb + 256 + col])) * tanhf_(cc);
        lds_hs[rl * 128 + col] = f2bf(cc);
        lds_fc[rl * 128 + col] = f2bf(hh);
      }
  }
  __syncthreads();
  // dense stores: 64 rows x 256 B each for c and h
  u16* cdst = c_out + m0 * 128;
  u16* hdst = h_out + m0 * 128;
#pragma unroll
  for (int i = 0; i < 4; i++) {
    const int c16 = tid * 4 + i;   // 1024 chunks
    *reinterpret_cast<uint4*>(cdst + c16 * 8) = *reinterpret_cast<const uint4*>(&lds_hs[c16 * 8]);
    *reinterpret_cast<uint4*>(hdst + c16 * 8) = *reinterpret_cast<const uint4*>(&lds_fc[c16 * 8]);
  }
}

// ---------- weight/bias prep ----------
__global__ void build_wallT(const float* __restrict__ Wix, const float* __restrict__ Wux,
                            const float* __restrict__ Wox, const float* __restrict__ Wfx,
                            u16* __restrict__ WT)
{
  int idx = blockIdx.x * 256 + threadIdx.x;   // 512*128
  int n = idx >> 7, k = idx & 127;
  int g = n >> 7, j = n & 127;
  const float* W = (g == 0) ? Wix : (g == 1) ? Wux : (g == 2) ? Wox : Wfx;
  WT[idx] = f2bf(W[k * 128 + j]);
}

__global__ void build_bsum(const float* __restrict__ b_ix, const float* __restrict__ b_ih,
                           const float* __restrict__ b_ux, const float* __restrict__ b_uh,
                           const float* __restrict__ b_ox, const float* __restrict__ b_oh,
                           const float* __restrict__ b_fx, const float* __restrict__ b_fh,
                           float* __restrict__ bsum)
{
  int n = blockIdx.x * 256 + threadIdx.x;   // 512
  int g = n >> 7, j = n & 127;
  float v = (g == 0) ? b_ix[j] + b_ih[j] : (g == 1) ? b_ux[j] + b_uh[j]
          : (g == 2) ? b_ox[j] + b_oh[j] : b_fx[j] + b_fh[j];
  bsum[n] = v;
}

__global__ void build_bt128(const float* __restrict__ W, u16* __restrict__ BT) {
  int idx = blockIdx.x * 256 + threadIdx.x;   // 128*128
  int n = idx >> 7, k = idx & 127;
  BT[idx] = f2bf(W[k * 128 + n]);
}

// ---------- output projection (4096 x 4, tiny) ----------
__global__ void out_proj(const u16* __restrict__ h_root, const float* __restrict__ W_out,
                         const float* __restrict__ b_out, float* __restrict__ out)
{
  int idx = blockIdx.x * 256 + threadIdx.x;   // 4096*4
  int n = idx >> 2, cls = idx & 3;
  float s = b_out[cls];
  for (int k = 0; k < 128; k++)
    s += bf2f(h_root[(long)n * 128 + k]) * W_out[k * 4 + cls];
  out[idx] = s;
}

extern "C" void kernel_launch(void* const* d_in, const int* in_sizes, int n_in,
                              void* d_out, int out_size, void* d_ws, size_t ws_size,
                              hipStream_t stream)
{
  const int*   sen  = (const int*)d_in[0];
  const float* emb  = (const float*)d_in[1];
  const float* W_ix = (const float*)d_in[2];  const float* b_ix = (const float*)d_in[3];
  const float* W_ih = (const float*)d_in[4];  const float* b_ih = (const float*)d_in[5];
  const float* W_fx = (const float*)d_in[6];  const float* b_fx = (const float*)d_in[7];
  const float* W_fh = (const float*)d_in[8];  const float* b_fh = (const float*)d_in[9];
  const float* W_ox = (const float*)d_in[10]; const float* b_ox = (const float*)d_in[11];
  const float* W_oh = (const float*)d_in[12]; const float* b_oh = (const float*)d_in[13];
  const float* W_ux = (const float*)d_in[14]; const float* b_ux = (const float*)d_in[15];
  const float* W_uh = (const float*)d_in[16]; const float* b_uh = (const float*)d_in[17];
  const float* W_out= (const float*)d_in[18]; const float* b_out= (const float*)d_in[19];
  float* out = (float*)d_out;

  // ---- workspace: 3 x 67.1 MB slots + E' 51.2 MB + small weights (~252.8 MB) ----
  const size_t SLOT = (size_t)262144 * 128 * 2;
  const size_t EPB  = (size_t)50000 * 512 * 2;
  const size_t need = 3 * SLOT + EPB + (size_t)512 * 128 * 2 + 4 * (size_t)128 * 128 * 2
                    + 512 * 4 + 8192;
  fprintf(stderr, "[tree_lstm] ws_size=%zu need=%zu\n", ws_size, need);
  if (ws_size < need) {
    fprintf(stderr, "[tree_lstm] INSUFFICIENT WORKSPACE — skipping launch\n");
    return;
  }
  char* ws = (char*)d_ws;
  size_t off = 0;
  auto take = [&](size_t bytes) { char* p = ws + off; off += (bytes + 255) & ~(size_t)255; return p; };
  u16* X    = (u16*)take(SLOT);                     // h_prev / h_cur (rotates with Y)
  u16* Bc   = (u16*)take(SLOT);                     // c (prev -> cur, sequenced)
  u16* Y    = (u16*)take(SLOT);                     // fcsum then h_cur (rotates with X)
  u16* Ep   = (u16*)take(EPB);
  u16* WallT= (u16*)take((size_t)512 * 128 * 2);
  u16* BihT = (u16*)take((size_t)128 * 128 * 2);
  u16* BuhT = (u16*)take((size_t)128 * 128 * 2);
  u16* BohT = (u16*)take((size_t)128 * 128 * 2);
  u16* BfhT = (u16*)take((size_t)128 * 128 * 2);
  float* bsum = (float*)take(512 * 4);

  // ---- prep ----
  build_wallT<<<256, 256, 0, stream>>>(W_ix, W_ux, W_ox, W_fx, WallT);
  build_bsum<<<2, 256, 0, stream>>>(b_ix, b_ih, b_ux, b_uh, b_ox, b_oh, b_fx, b_fh, bsum);
  build_bt128<<<64, 256, 0, stream>>>(W_ih, BihT);
  build_bt128<<<64, 256, 0, stream>>>(W_uh, BuhT);
  build_bt128<<<64, 256, 0, stream>>>(W_oh, BohT);
  build_bt128<<<64, 256, 0, stream>>>(W_fh, BfhT);
  proj_e<<<dim3(391, 4), 256, 0, stream>>>(emb, WallT, bsum, Ep);

  const long LOFF[6] = {0, 4096, 20480, 86016, 217088, 479232};
  const int  LSZ[6]  = {4096, 16384, 65536, 131072, 262144, 262144};
  const int  LLR[5]  = {2, 2, 1, 1, 0};   // log2(children per node), L=0..4

  // ---- leaf level L=5: elementwise from E'. c->Bc, h->Y ----
  k_leaf<<<LSZ[5] / 128, 256, 0, stream>>>(sen, Ep, Bc, Y, LOFF[5]);
  { u16* t = X; X = Y; Y = t; }

  // ---- levels 4..0 ----
  for (int L = 4; L >= 0; L--) {
    const long o0 = LOFF[L];
    const int nL = LSZ[L], nC = LSZ[L + 1];
    const int lr = LLR[L], ratio = 1 << lr;
    k_fc<<<nC / 64, 256, 0, stream>>>(sen, Ep, X, Bc, BfhT, Y, o0, lr);
    k_cell<<<nL / 64, 256, 0, stream>>>(sen, Ep, X, BihT, BuhT, BohT,
        Y, Bc, Y, o0, ratio);
    u16* t = X; X = Y; Y = t;
  }

  out_proj<<<64, 256, 0, stream>>>(X, W_out, b_out, out);
}

// Round 7
// 726.563 us; speedup vs baseline: 1.7007x; 1.2571x over previous
//
#include <hip/hip_runtime.h>
#include <cstdio>

typedef unsigned short u16;
typedef __bf16 bf16x8 __attribute__((ext_vector_type(8)));
typedef float  floatx4 __attribute__((ext_vector_type(4)));

// ---------- scalar helpers ----------
__device__ __forceinline__ float bf2f(u16 u) {
  union { unsigned int i; float f; } v; v.i = ((unsigned int)u) << 16; return v.f;
}
__device__ __forceinline__ u16 f2bf(float f) {
  union { float f; unsigned int i; } v; v.f = f;
  unsigned int x = v.i;
  return (u16)((x + 0x7fffu + ((x >> 16) & 1u)) >> 16);   // RNE
}
__device__ __forceinline__ float sigmoidf_(float x) { return 1.f / (1.f + __expf(-x)); }
__device__ __forceinline__ float tanhf_(float x) {
  float ax = fabsf(x);
  float e = __expf(-2.f * ax);
  return copysignf((1.f - e) / (1.f + e), x);
}

// LDS swizzle for 128-elem rows (16 chunks of 16B): chunk' = chunk ^ (row&15)
__device__ __forceinline__ int swz128(int row, int c16) {
  return row * 128 + ((c16 ^ (row & 15)) << 3);
}

// ============ proj_e: E'[v][512] = emb[v] @ [Wix|Wux|Wox|Wfx] + bias (bf16) ============
__global__ __launch_bounds__(256) void proj_e(
    const float* __restrict__ emb, const u16* __restrict__ WT,
    const float* __restrict__ bsum, u16* __restrict__ Ep)
{
  __shared__ __align__(16) u16 ldsA[128 * 128];
  const int tid = threadIdx.x;
  const long m0 = (long)blockIdx.x * 128;
  const int n0 = blockIdx.y * 128;
  {
    const int r = tid >> 1, half = tid & 1;
    long row = m0 + r; if (row > 49999) row = 49999;
    const float* src = emb + row * 128 + half * 64;
#pragma unroll
    for (int i = 0; i < 8; i++) {
      float4 v0 = *reinterpret_cast<const float4*>(src + i * 8);
      float4 v1 = *reinterpret_cast<const float4*>(src + i * 8 + 4);
      u16 ov[8] = { f2bf(v0.x), f2bf(v0.y), f2bf(v0.z), f2bf(v0.w),
                    f2bf(v1.x), f2bf(v1.y), f2bf(v1.z), f2bf(v1.w) };
      *reinterpret_cast<uint4*>(&ldsA[swz128(r, half * 8 + i)]) =
          *reinterpret_cast<const uint4*>(ov);
    }
  }
  __syncthreads();
  const int lane = tid & 63, w = tid >> 6, l16 = lane & 15, quad = lane >> 4;
#pragma unroll
  for (int gl = 0; gl < 2; gl++) {
    const int col = n0 + w * 32 + gl * 16 + l16;
    bf16x8 b[4];
#pragma unroll
    for (int ks = 0; ks < 4; ks++)
      b[ks] = *reinterpret_cast<const bf16x8*>(WT + (size_t)col * 128 + ks * 32 + quad * 8);
    floatx4 acc[8];
#pragma unroll
    for (int i = 0; i < 8; i++) acc[i] = (floatx4){0.f, 0.f, 0.f, 0.f};
#pragma unroll
    for (int ks = 0; ks < 4; ks++)
#pragma unroll
      for (int i = 0; i < 8; i++) {
        bf16x8 a = *reinterpret_cast<const bf16x8*>(&ldsA[swz128(i * 16 + l16, ks * 4 + quad)]);
        acc[i] = __builtin_amdgcn_mfma_f32_16x16x32_bf16(a, b[ks], acc[i], 0, 0, 0);
      }
    const float bb = bsum[col];
#pragma unroll
    for (int i = 0; i < 8; i++)
#pragma unroll
      for (int r2 = 0; r2 < 4; r2++) {
        const long row = m0 + i * 16 + quad * 4 + r2;
        if (row < 50000) Ep[row * 512 + col] = f2bf(acc[i][r2] + bb);
      }
  }
}

// ============ k_level: fused f + i/u/o + cell update for one level ============
// Parents p0..p0+PM-1 and their CM = PM<<LR children (contiguous).
// LEAF: child h,c computed from Ep rows in staging (no HBM h/c for leaves).
// fcsum stays in LDS (col-partitioned per wave -> writer wave == reader wave).
template<int LR, bool LEAF>
__global__ __launch_bounds__(256, 2) void k_level(
    const int* __restrict__ sen, const u16* __restrict__ Ep,
    const u16* __restrict__ h_prev, const u16* __restrict__ c_prev,
    const u16* __restrict__ BfT, const u16* __restrict__ BihT,
    const u16* __restrict__ BuhT, const u16* __restrict__ BohT,
    u16* __restrict__ c_out, u16* __restrict__ h_out,
    long o0, long co0)
{
  constexpr int PM  = (LR == 2) ? 32 : 64;
  constexpr int CM  = PM << LR;
  constexpr int NI  = PM / 16;
  constexpr int NCI = CM / 16;
  constexpr int TPR = 256 / CM;        // staging threads per child row
  constexpr int RT  = 1 << LR;
  __shared__ __align__(16) u16 ldsA[CM * 128];                  // child h (swz); h-stage (LR>=1)
  __shared__ __align__(16) u16 ldsS[(LR >= 1) ? PM * 128 : 8];  // h_sum (swz)
  __shared__ __align__(16) u16 ldsF[PM * 128];                  // fcsum -> c (linear)
  __shared__ __align__(16) u16 ldsC[LEAF ? CM * 128 : 8];       // leaf child c; leaf h-stage
  __shared__ int sidP[PM];

  const int tid = threadIdx.x;
  const long p0 = (long)blockIdx.x * PM;
  const long cb = (long)blockIdx.x * CM;

  // ---- stage children ----
  {
    const int r = tid / TPR, q = tid % TPR;
    constexpr int CH = 16 / TPR;
    if (LEAF) {
      const u16* e = Ep + (size_t)sen[co0 + cb + r] * 512;
#pragma unroll
      for (int ii = 0; ii < CH; ii++) {
        const int c16 = q * CH + ii;
        uint4 vi = *reinterpret_cast<const uint4*>(e + c16 * 8);
        uint4 vu = *reinterpret_cast<const uint4*>(e + 128 + c16 * 8);
        uint4 vo = *reinterpret_cast<const uint4*>(e + 256 + c16 * 8);
        const u16* pi = reinterpret_cast<const u16*>(&vi);
        const u16* pu = reinterpret_cast<const u16*>(&vu);
        const u16* po = reinterpret_cast<const u16*>(&vo);
        u16 hc[8], cc[8];
#pragma unroll
        for (int k = 0; k < 8; k++) {
          float cv = sigmoidf_(bf2f(pi[k])) * tanhf_(bf2f(pu[k]));
          cc[k] = f2bf(cv);
          hc[k] = f2bf(sigmoidf_(bf2f(po[k])) * tanhf_(cv));
        }
        *reinterpret_cast<uint4*>(&ldsA[swz128(r, c16)]) = *reinterpret_cast<const uint4*>(hc);
        *reinterpret_cast<uint4*>(&ldsC[r * 128 + c16 * 8]) = *reinterpret_cast<const uint4*>(cc);
      }
    } else {
      const u16* src = h_prev + (cb + r) * 128;
#pragma unroll
      for (int ii = 0; ii < CH; ii++) {
        const int c16 = q * CH + ii;
        *reinterpret_cast<uint4*>(&ldsA[swz128(r, c16)]) =
            *reinterpret_cast<const uint4*>(src + c16 * 8);
      }
    }
    if (tid < PM) sidP[tid] = sen[o0 + p0 + tid];
  }
  __syncthreads();

  // ---- h_sum (LR>=1): sum ratio child rows from LDS ----
  if (LR >= 1) {
    for (int t = tid; t < PM * 16; t += 256) {
      const int row = t >> 4, c16 = t & 15;
      float s8[8] = {0.f, 0.f, 0.f, 0.f, 0.f, 0.f, 0.f, 0.f};
#pragma unroll
      for (int cr = 0; cr < RT; cr++) {
        uint4 v = *reinterpret_cast<const uint4*>(&ldsA[swz128(row * RT + cr, c16)]);
        const u16* p = reinterpret_cast<const u16*>(&v);
#pragma unroll
        for (int e = 0; e < 8; e++) s8[e] += bf2f(p[e]);
      }
      u16 ov[8];
#pragma unroll
      for (int e = 0; e < 8; e++) ov[e] = f2bf(s8[e]);
      *reinterpret_cast<uint4*>(&ldsS[swz128(row, c16)]) = *reinterpret_cast<const uint4*>(ov);
    }
    __syncthreads();
  }

  const int lane = tid & 63, w = tid >> 6, l16 = lane & 15, quad = lane >> 4;
  const u16* As = (LR == 0) ? ldsA : ldsS;   // parent GEMM A operand

  // ---- f GEMM over child rows + epilogue -> fcsum into ldsF ----
#pragma unroll
  for (int gl = 0; gl < 2; gl++) {
    const int col = w * 32 + gl * 16 + l16;
    bf16x8 b[4];
#pragma unroll
    for (int ks = 0; ks < 4; ks++)
      b[ks] = *reinterpret_cast<const bf16x8*>(BfT + (size_t)col * 128 + ks * 32 + quad * 8);
    floatx4 acc[NCI];
#pragma unroll
    for (int i = 0; i < NCI; i++) acc[i] = (floatx4){0.f, 0.f, 0.f, 0.f};
#pragma unroll
    for (int ks = 0; ks < 4; ks++)
#pragma unroll
      for (int i = 0; i < NCI; i++) {
        bf16x8 a = *reinterpret_cast<const bf16x8*>(&ldsA[swz128(i * 16 + l16, ks * 4 + quad)]);
        acc[i] = __builtin_amdgcn_mfma_f32_16x16x32_bf16(a, b[ks], acc[i], 0, 0, 0);
      }
#pragma unroll
    for (int i = 0; i < NCI; i++) {
      const int rbase = i * 16 + quad * 4;
      float fcv[4];
#pragma unroll
      for (int r2 = 0; r2 < 4; r2++) {
        const int row = rbase + r2;
        const float pre = acc[i][r2] + bf2f(Ep[(size_t)sidP[row >> LR] * 512 + 384 + col]);
        const float cch = LEAF ? bf2f(ldsC[row * 128 + col])
                               : bf2f(c_prev[(cb + row) * 128 + col]);
        fcv[r2] = sigmoidf_(pre) * cch;
      }
      if (LR == 2) {
        ldsF[(rbase >> 2) * 128 + col] = f2bf(fcv[0] + fcv[1] + fcv[2] + fcv[3]);
      } else if (LR == 1) {
        ldsF[(rbase >> 1) * 128 + col]       = f2bf(fcv[0] + fcv[1]);
        ldsF[((rbase >> 1) + 1) * 128 + col] = f2bf(fcv[2] + fcv[3]);
      } else {
#pragma unroll
        for (int r2 = 0; r2 < 4; r2++)
          ldsF[(rbase + r2) * 128 + col] = f2bf(fcv[r2]);
      }
    }
  }
  if (LR >= 1) __syncthreads();   // release ldsA for h-stage reuse

  // ---- i/u GEMMs + epilogue: c overwrites ldsF in place; tanh(c) kept in regs ----
  float tch[2][NI][4];
#pragma unroll
  for (int gl = 0; gl < 2; gl++) {
    const int col = w * 32 + gl * 16 + l16;
    bf16x8 bi[4], bu[4];
#pragma unroll
    for (int ks = 0; ks < 4; ks++) {
      bi[ks] = *reinterpret_cast<const bf16x8*>(BihT + (size_t)col * 128 + ks * 32 + quad * 8);
      bu[ks] = *reinterpret_cast<const bf16x8*>(BuhT + (size_t)col * 128 + ks * 32 + quad * 8);
    }
    floatx4 aI[NI], aU[NI];
#pragma unroll
    for (int i = 0; i < NI; i++) { aI[i] = (floatx4){0.f,0.f,0.f,0.f}; aU[i] = (floatx4){0.f,0.f,0.f,0.f}; }
#pragma unroll
    for (int ks = 0; ks < 4; ks++)
#pragma unroll
      for (int i = 0; i < NI; i++) {
        bf16x8 a = *reinterpret_cast<const bf16x8*>(&As[swz128(i * 16 + l16, ks * 4 + quad)]);
        aI[i] = __builtin_amdgcn_mfma_f32_16x16x32_bf16(a, bi[ks], aI[i], 0, 0, 0);
        aU[i] = __builtin_amdgcn_mfma_f32_16x16x32_bf16(a, bu[ks], aU[i], 0, 0, 0);
      }
#pragma unroll
    for (int i = 0; i < NI; i++)
#pragma unroll
      for (int r2 = 0; r2 < 4; r2++) {
        const int rl = i * 16 + quad * 4 + r2;
        const size_t eb = (size_t)sidP[rl] * 512;
        const float preI = aI[i][r2] + bf2f(Ep[eb + col]);
        const float preU = aU[i][r2] + bf2f(Ep[eb + 128 + col]);
        const float cv = sigmoidf_(preI) * tanhf_(preU) + bf2f(ldsF[rl * 128 + col]);
        ldsF[rl * 128 + col] = f2bf(cv);
        tch[gl][i][r2] = tanhf_(cv);
      }
  }

  // ---- o GEMM (both col-groups) + epilogue: h into stage ----
  u16* hstage = (LR == 0) ? (u16*)ldsC : (u16*)ldsA;   // both dead by now (col/own-wave safe)
  bf16x8 bo[2][4];
#pragma unroll
  for (int gl = 0; gl < 2; gl++)
#pragma unroll
    for (int ks = 0; ks < 4; ks++)
      bo[gl][ks] = *reinterpret_cast<const bf16x8*>(
          BohT + (size_t)(w * 32 + gl * 16 + l16) * 128 + ks * 32 + quad * 8);
  floatx4 aO[2][NI];
#pragma unroll
  for (int gl = 0; gl < 2; gl++)
#pragma unroll
    for (int i = 0; i < NI; i++) aO[gl][i] = (floatx4){0.f, 0.f, 0.f, 0.f};
#pragma unroll
  for (int ks = 0; ks < 4; ks++)
#pragma unroll
    for (int i = 0; i < NI; i++) {
      bf16x8 a = *reinterpret_cast<const bf16x8*>(&As[swz128(i * 16 + l16, ks * 4 + quad)]);
#pragma unroll
      for (int gl = 0; gl < 2; gl++)
        aO[gl][i] = __builtin_amdgcn_mfma_f32_16x16x32_bf16(a, bo[gl][ks], aO[gl][i], 0, 0, 0);
    }
#pragma unroll
  for (int gl = 0; gl < 2; gl++) {
    const int col = w * 32 + gl * 16 + l16;
#pragma unroll
    for (int i = 0; i < NI; i++)
#pragma unroll
      for (int r2 = 0; r2 < 4; r2++) {
        const int rl = i * 16 + quad * 4 + r2;
        const size_t eb = (size_t)sidP[rl] * 512;
        const float hh = sigmoidf_(aO[gl][i][r2] + bf2f(Ep[eb + 256 + col])) * tch[gl][i][r2];
        hstage[rl * 128 + col] = f2bf(hh);
      }
  }
  __syncthreads();

  // ---- dense stores: c from ldsF, h from hstage ----
  u16* cdst = c_out + p0 * 128;
  u16* hdst = h_out + p0 * 128;
  for (int t = tid; t < PM * 16; t += 256) {
    *reinterpret_cast<uint4*>(cdst + t * 8) = *reinterpret_cast<const uint4*>(&ldsF[t * 8]);
    *reinterpret_cast<uint4*>(hdst + t * 8) = *reinterpret_cast<const uint4*>(&hstage[t * 8]);
  }
}

// ---------- weight/bias prep ----------
__global__ void build_wallT(const float* __restrict__ Wix, const float* __restrict__ Wux,
                            const float* __restrict__ Wox, const float* __restrict__ Wfx,
                            u16* __restrict__ WT)
{
  int idx = blockIdx.x * 256 + threadIdx.x;   // 512*128
  int n = idx >> 7, k = idx & 127;
  int g = n >> 7, j = n & 127;
  const float* W = (g == 0) ? Wix : (g == 1) ? Wux : (g == 2) ? Wox : Wfx;
  WT[idx] = f2bf(W[k * 128 + j]);
}

__global__ void build_bsum(const float* __restrict__ b_ix, const float* __restrict__ b_ih,
                           const float* __restrict__ b_ux, const float* __restrict__ b_uh,
                           const float* __restrict__ b_ox, const float* __restrict__ b_oh,
                           const float* __restrict__ b_fx, const float* __restrict__ b_fh,
                           float* __restrict__ bsum)
{
  int n = blockIdx.x * 256 + threadIdx.x;   // 512
  int g = n >> 7, j = n & 127;
  float v = (g == 0) ? b_ix[j] + b_ih[j] : (g == 1) ? b_ux[j] + b_uh[j]
          : (g == 2) ? b_ox[j] + b_oh[j] : b_fx[j] + b_fh[j];
  bsum[n] = v;
}

__global__ void build_bt128(const float* __restrict__ W, u16* __restrict__ BT) {
  int idx = blockIdx.x * 256 + threadIdx.x;   // 128*128
  int n = idx >> 7, k = idx & 127;
  BT[idx] = f2bf(W[k * 128 + n]);
}

// ---------- output projection (4096 x 4, tiny) ----------
__global__ void out_proj(const u16* __restrict__ h_root, const float* __restrict__ W_out,
                         const float* __restrict__ b_out, float* __restrict__ out)
{
  int idx = blockIdx.x * 256 + threadIdx.x;   // 4096*4
  int n = idx >> 2, cls = idx & 3;
  float s = b_out[cls];
  for (int k = 0; k < 128; k++)
    s += bf2f(h_root[(long)n * 128 + k]) * W_out[k * 4 + cls];
  out[idx] = s;
}

extern "C" void kernel_launch(void* const* d_in, const int* in_sizes, int n_in,
                              void* d_out, int out_size, void* d_ws, size_t ws_size,
                              hipStream_t stream)
{
  const int*   sen  = (const int*)d_in[0];
  const float* emb  = (const float*)d_in[1];
  const float* W_ix = (const float*)d_in[2];  const float* b_ix = (const float*)d_in[3];
  const float* W_ih = (const float*)d_in[4];  const float* b_ih = (const float*)d_in[5];
  const float* W_fx = (const float*)d_in[6];  const float* b_fx = (const float*)d_in[7];
  const float* W_fh = (const float*)d_in[8];  const float* b_fh = (const float*)d_in[9];
  const float* W_ox = (const float*)d_in[10]; const float* b_ox = (const float*)d_in[11];
  const float* W_oh = (const float*)d_in[12]; const float* b_oh = (const float*)d_in[13];
  const float* W_ux = (const float*)d_in[14]; const float* b_ux = (const float*)d_in[15];
  const float* W_uh = (const float*)d_in[16]; const float* b_uh = (const float*)d_in[17];
  const float* W_out= (const float*)d_in[18]; const float* b_out= (const float*)d_in[19];
  float* out = (float*)d_out;

  // ---- workspace: arena A (L4/L2/L0 h+c), arena B (L3/L1 h+c), Ep, weights ----
  const size_t AH = (size_t)262144 * 128;   // u16 elems
  const size_t BH = (size_t)131072 * 128;
  const size_t EPB = (size_t)50000 * 512 * 2;
  const size_t need = 2 * AH * 2 + 2 * BH * 2 + EPB
                    + (size_t)512 * 128 * 2 + 4 * (size_t)128 * 128 * 2 + 512 * 4 + 8192;
  fprintf(stderr, "[tree_lstm] ws_size=%zu need=%zu\n", ws_size, need);
  if (ws_size < need) {
    fprintf(stderr, "[tree_lstm] INSUFFICIENT WORKSPACE — skipping launch\n");
    return;
  }
  char* ws = (char*)d_ws;
  size_t off = 0;
  auto take = [&](size_t bytes) { char* p = ws + off; off += (bytes + 255) & ~(size_t)255; return p; };
  u16* hA = (u16*)take(AH * 2);
  u16* cA = (u16*)take(AH * 2);
  u16* hB = (u16*)take(BH * 2);
  u16* cB = (u16*)take(BH * 2);
  u16* Ep = (u16*)take(EPB);
  u16* WallT = (u16*)take((size_t)512 * 128 * 2);
  u16* BihT = (u16*)take((size_t)128 * 128 * 2);
  u16* BuhT = (u16*)take((size_t)128 * 128 * 2);
  u16* BohT = (u16*)take((size_t)128 * 128 * 2);
  u16* BfhT = (u16*)take((size_t)128 * 128 * 2);
  float* bsum = (float*)take(512 * 4);

  // ---- prep ----
  build_wallT<<<256, 256, 0, stream>>>(W_ix, W_ux, W_ox, W_fx, WallT);
  build_bsum<<<2, 256, 0, stream>>>(b_ix, b_ih, b_ux, b_uh, b_ox, b_oh, b_fx, b_fh, bsum);
  build_bt128<<<64, 256, 0, stream>>>(W_ih, BihT);
  build_bt128<<<64, 256, 0, stream>>>(W_uh, BuhT);
  build_bt128<<<64, 256, 0, stream>>>(W_oh, BohT);
  build_bt128<<<64, 256, 0, stream>>>(W_fh, BfhT);
  proj_e<<<dim3(391, 4), 256, 0, stream>>>(emb, WallT, bsum, Ep);

  const long LOFF[6] = {0, 4096, 20480, 86016, 217088, 479232};

  // L4 (parents 262144, leaf children from Ep) -> A
  k_level<0, true><<<4096, 256, 0, stream>>>(sen, Ep, nullptr, nullptr,
      BfhT, BihT, BuhT, BohT, cA, hA, LOFF[4], LOFF[5]);
  // L3 (131072, ratio 2) A -> B
  k_level<1, false><<<2048, 256, 0, stream>>>(sen, Ep, hA, cA,
      BfhT, BihT, BuhT, BohT, cB, hB, LOFF[3], 0);
  // L2 (65536, ratio 2) B -> A
  k_level<1, false><<<1024, 256, 0, stream>>>(sen, Ep, hB, cB,
      BfhT, BihT, BuhT, BohT, cA, hA, LOFF[2], 0);
  // L1 (16384, ratio 4) A -> B
  k_level<2, false><<<512, 256, 0, stream>>>(sen, Ep, hA, cA,
      BfhT, BihT, BuhT, BohT, cB, hB, LOFF[1], 0);
  // L0 (4096, ratio 4) B -> A
  k_level<2, false><<<128, 256, 0, stream>>>(sen, Ep, hB, cB,
      BfhT, BihT, BuhT, BohT, cA, hA, LOFF[0], 0);

  out_proj<<<64, 256, 0, stream>>>(hA, W_out, b_out, out);
}

// Round 8
// 647.030 us; speedup vs baseline: 1.9097x; 1.1229x over previous
//
#include <hip/hip_runtime.h>
#include <hip/hip_bf16.h>
#include <cstdio>

typedef unsigned short u16;
typedef __bf16 bf16x8 __attribute__((ext_vector_type(8)));
typedef float  floatx4 __attribute__((ext_vector_type(4)));

// ---------- scalar helpers ----------
__device__ __forceinline__ float bf2f(u16 u) {
  union { unsigned int i; float f; } v; v.i = ((unsigned int)u) << 16; return v.f;
}
__device__ __forceinline__ u16 f2bf(float f) {
  union { float f; unsigned int i; } v; v.f = f;
  unsigned int x = v.i;
  return (u16)((x + 0x7fffu + ((x >> 16) & 1u)) >> 16);   // RNE
}
__device__ __forceinline__ unsigned int f2bf_pk(float a, float b) {   // [lo=a, hi=b]
  __hip_bfloat162 h = __float22bfloat162_rn(make_float2(a, b));
  union { __hip_bfloat162 h; unsigned int u; } v; v.h = h; return v.u;
}
// fast gates: v_rcp (~1 ulp) + native exp — no IEEE div, no copysign
__device__ __forceinline__ float sigmoidf_(float x) {
  return __builtin_amdgcn_rcpf(1.f + __expf(-x));
}
__device__ __forceinline__ float tanhf_(float x) {
  return fmaf(-2.f, __builtin_amdgcn_rcpf(1.f + __expf(2.f * x)), 1.f);
}

// LDS swizzle, 128-elem rows, 16B chunks: chunk' = chunk ^ (row&15)
__device__ __forceinline__ int swz128(int row, int c16) {
  return row * 128 + ((c16 ^ (row & 15)) << 3);
}
// element-level swizzled index (scalar epilogue access into swizzled rows)
__device__ __forceinline__ int swze(int row, int col) {
  return row * 128 + (((((col >> 3)) ^ (row & 15)) << 3) | (col & 7));
}

// ============ proj_e: E'[v][512] = emb[v] @ [Wix|Wux|Wox|Wfx] + bias (bf16) ============
__global__ __launch_bounds__(256) void proj_e(
    const float* __restrict__ emb, const u16* __restrict__ WT,
    const float* __restrict__ bsum, u16* __restrict__ Ep)
{
  __shared__ __align__(16) u16 ldsA[128 * 128];
  const int tid = threadIdx.x;
  const long m0 = (long)blockIdx.x * 128;
  const int n0 = blockIdx.y * 128;
  {
    const int r = tid >> 1, half = tid & 1;
    long row = m0 + r; if (row > 49999) row = 49999;
    const float* src = emb + row * 128 + half * 64;
#pragma unroll
    for (int i = 0; i < 8; i++) {
      float4 v0 = *reinterpret_cast<const float4*>(src + i * 8);
      float4 v1 = *reinterpret_cast<const float4*>(src + i * 8 + 4);
      unsigned int ov[4] = { f2bf_pk(v0.x, v0.y), f2bf_pk(v0.z, v0.w),
                             f2bf_pk(v1.x, v1.y), f2bf_pk(v1.z, v1.w) };
      *reinterpret_cast<uint4*>(&ldsA[swz128(r, half * 8 + i)]) =
          *reinterpret_cast<const uint4*>(ov);
    }
  }
  __syncthreads();
  const int lane = tid & 63, w = tid >> 6, l16 = lane & 15, quad = lane >> 4;
#pragma unroll
  for (int gl = 0; gl < 2; gl++) {
    const int col = n0 + w * 32 + gl * 16 + l16;
    bf16x8 b[4];
#pragma unroll
    for (int ks = 0; ks < 4; ks++)
      b[ks] = *reinterpret_cast<const bf16x8*>(WT + (size_t)col * 128 + ks * 32 + quad * 8);
    floatx4 acc[8];
#pragma unroll
    for (int i = 0; i < 8; i++) acc[i] = (floatx4){0.f, 0.f, 0.f, 0.f};
#pragma unroll
    for (int ks = 0; ks < 4; ks++)
#pragma unroll
      for (int i = 0; i < 8; i++) {
        bf16x8 a = *reinterpret_cast<const bf16x8*>(&ldsA[swz128(i * 16 + l16, ks * 4 + quad)]);
        acc[i] = __builtin_amdgcn_mfma_f32_16x16x32_bf16(a, b[ks], acc[i], 0, 0, 0);
      }
    const float bb = bsum[col];
#pragma unroll
    for (int i = 0; i < 8; i++)
#pragma unroll
      for (int r2 = 0; r2 < 4; r2++) {
        const long row = m0 + i * 16 + quad * 4 + r2;
        if (row < 50000) Ep[row * 512 + col] = f2bf(acc[i][r2] + bb);
      }
  }
}

// ============ k_level: fused f + i/u/o + cell update for one level ============
template<int LR, bool LEAF>
__global__ __launch_bounds__(256, 2) void k_level(
    const int* __restrict__ sen, const u16* __restrict__ Ep,
    const u16* __restrict__ h_prev, const u16* __restrict__ c_prev,
    const u16* __restrict__ BfT, const u16* __restrict__ BihT,
    const u16* __restrict__ BuhT, const u16* __restrict__ BohT,
    u16* __restrict__ c_out, u16* __restrict__ h_out,
    long o0, long co0)
{
  constexpr int PM  = (LR == 2) ? 32 : 64;
  constexpr int CM  = PM << LR;
  constexpr int NI  = PM / 16;
  constexpr int NCI = CM / 16;
  constexpr int TPR = 256 / CM;        // staging threads per child row
  constexpr int RT  = 1 << LR;
  __shared__ __align__(16) u16 ldsA[CM * 128];                  // child h (swz); h-stage (LR>=1)
  __shared__ __align__(16) u16 ldsS[(LR >= 1) ? PM * 128 : 8];  // h_sum (swz)
  __shared__ __align__(16) u16 ldsF[PM * 128];                  // fcsum -> c (swz)
  __shared__ __align__(16) u16 ldsC[LEAF ? CM * 128 : 8];       // leaf child c (swz); leaf h-stage
  __shared__ int sidP[PM];

  const int tid = threadIdx.x;
  const long p0 = (long)blockIdx.x * PM;
  const long cb = (long)blockIdx.x * CM;

  // ---- stage children ----
  {
    const int r = tid / TPR, q = tid % TPR;
    constexpr int CH = 16 / TPR;
    if (LEAF) {
      const u16* e = Ep + (size_t)sen[co0 + cb + r] * 512;
#pragma unroll
      for (int ii = 0; ii < CH; ii++) {
        const int c16 = q * CH + ii;
        uint4 vi = *reinterpret_cast<const uint4*>(e + c16 * 8);
        uint4 vu = *reinterpret_cast<const uint4*>(e + 128 + c16 * 8);
        uint4 vo = *reinterpret_cast<const uint4*>(e + 256 + c16 * 8);
        const u16* pi = reinterpret_cast<const u16*>(&vi);
        const u16* pu = reinterpret_cast<const u16*>(&vu);
        const u16* po = reinterpret_cast<const u16*>(&vo);
        unsigned int hc[4], cc[4];
#pragma unroll
        for (int k = 0; k < 4; k++) {
          float cv0 = sigmoidf_(bf2f(pi[2*k]))   * tanhf_(bf2f(pu[2*k]));
          float cv1 = sigmoidf_(bf2f(pi[2*k+1])) * tanhf_(bf2f(pu[2*k+1]));
          float h0 = sigmoidf_(bf2f(po[2*k]))   * tanhf_(cv0);
          float h1 = sigmoidf_(bf2f(po[2*k+1])) * tanhf_(cv1);
          cc[k] = f2bf_pk(cv0, cv1);
          hc[k] = f2bf_pk(h0, h1);
        }
        *reinterpret_cast<uint4*>(&ldsA[swz128(r, c16)]) = *reinterpret_cast<const uint4*>(hc);
        *reinterpret_cast<uint4*>(&ldsC[swz128(r, c16)]) = *reinterpret_cast<const uint4*>(cc);
      }
    } else {
      const u16* src = h_prev + (cb + r) * 128;
#pragma unroll
      for (int ii = 0; ii < CH; ii++) {
        const int c16 = q * CH + ii;
        *reinterpret_cast<uint4*>(&ldsA[swz128(r, c16)]) =
            *reinterpret_cast<const uint4*>(src + c16 * 8);
      }
    }
    if (tid < PM) sidP[tid] = sen[o0 + p0 + tid];
  }
  __syncthreads();

  // ---- h_sum (LR>=1): sum ratio child rows from LDS ----
  if (LR >= 1) {
    for (int t = tid; t < PM * 16; t += 256) {
      const int row = t >> 4, c16 = t & 15;
      float s8[8] = {0.f, 0.f, 0.f, 0.f, 0.f, 0.f, 0.f, 0.f};
#pragma unroll
      for (int cr = 0; cr < RT; cr++) {
        uint4 v = *reinterpret_cast<const uint4*>(&ldsA[swz128(row * RT + cr, c16)]);
        const u16* p = reinterpret_cast<const u16*>(&v);
#pragma unroll
        for (int e = 0; e < 8; e++) s8[e] += bf2f(p[e]);
      }
      unsigned int ov[4] = { f2bf_pk(s8[0], s8[1]), f2bf_pk(s8[2], s8[3]),
                             f2bf_pk(s8[4], s8[5]), f2bf_pk(s8[6], s8[7]) };
      *reinterpret_cast<uint4*>(&ldsS[swz128(row, c16)]) = *reinterpret_cast<const uint4*>(ov);
    }
    __syncthreads();
  }

  const int lane = tid & 63, w = tid >> 6, l16 = lane & 15, quad = lane >> 4;
  const u16* As = (LR == 0) ? ldsA : ldsS;   // parent GEMM A operand

  // ---- f GEMM over child rows + epilogue -> fcsum into ldsF ----
#pragma unroll
  for (int gl = 0; gl < 2; gl++) {
    const int col = w * 32 + gl * 16 + l16;
    bf16x8 b[4];
#pragma unroll
    for (int ks = 0; ks < 4; ks++)
      b[ks] = *reinterpret_cast<const bf16x8*>(BfT + (size_t)col * 128 + ks * 32 + quad * 8);
    floatx4 acc[NCI];
#pragma unroll
    for (int i = 0; i < NCI; i++) acc[i] = (floatx4){0.f, 0.f, 0.f, 0.f};
#pragma unroll
    for (int ks = 0; ks < 4; ks++)
#pragma unroll
      for (int i = 0; i < NCI; i++) {
        bf16x8 a = *reinterpret_cast<const bf16x8*>(&ldsA[swz128(i * 16 + l16, ks * 4 + quad)]);
        acc[i] = __builtin_amdgcn_mfma_f32_16x16x32_bf16(a, b[ks], acc[i], 0, 0, 0);
      }
#pragma unroll
    for (int i = 0; i < NCI; i++) {
      const int rbase = i * 16 + quad * 4;
      float fcv[4];
#pragma unroll
      for (int r2 = 0; r2 < 4; r2++) {
        const int row = rbase + r2;
        const float pre = acc[i][r2] + bf2f(Ep[(size_t)sidP[row >> LR] * 512 + 384 + col]);
        const float cch = LEAF ? bf2f(ldsC[swze(row, col)])
                               : bf2f(c_prev[(cb + row) * 128 + col]);
        fcv[r2] = sigmoidf_(pre) * cch;
      }
      if (LR == 2) {
        ldsF[swze(rbase >> 2, col)] = f2bf(fcv[0] + fcv[1] + fcv[2] + fcv[3]);
      } else if (LR == 1) {
        ldsF[swze(rbase >> 1, col)]       = f2bf(fcv[0] + fcv[1]);
        ldsF[swze((rbase >> 1) + 1, col)] = f2bf(fcv[2] + fcv[3]);
      } else {
#pragma unroll
        for (int r2 = 0; r2 < 4; r2++)
          ldsF[swze(rbase + r2, col)] = f2bf(fcv[r2]);
      }
    }
  }
  if (LR >= 1) __syncthreads();   // release ldsA for h-stage reuse

  // ---- i/u GEMMs + epilogue: c overwrites ldsF in place; tanh(c) kept in regs ----
  float tch[2][NI][4];
#pragma unroll
  for (int gl = 0; gl < 2; gl++) {
    const int col = w * 32 + gl * 16 + l16;
    bf16x8 bi[4], bu[4];
#pragma unroll
    for (int ks = 0; ks < 4; ks++) {
      bi[ks] = *reinterpret_cast<const bf16x8*>(BihT + (size_t)col * 128 + ks * 32 + quad * 8);
      bu[ks] = *reinterpret_cast<const bf16x8*>(BuhT + (size_t)col * 128 + ks * 32 + quad * 8);
    }
    floatx4 aI[NI], aU[NI];
#pragma unroll
    for (int i = 0; i < NI; i++) { aI[i] = (floatx4){0.f,0.f,0.f,0.f}; aU[i] = (floatx4){0.f,0.f,0.f,0.f}; }
#pragma unroll
    for (int ks = 0; ks < 4; ks++)
#pragma unroll
      for (int i = 0; i < NI; i++) {
        bf16x8 a = *reinterpret_cast<const bf16x8*>(&As[swz128(i * 16 + l16, ks * 4 + quad)]);
        aI[i] = __builtin_amdgcn_mfma_f32_16x16x32_bf16(a, bi[ks], aI[i], 0, 0, 0);
        aU[i] = __builtin_amdgcn_mfma_f32_16x16x32_bf16(a, bu[ks], aU[i], 0, 0, 0);
      }
#pragma unroll
    for (int i = 0; i < NI; i++)
#pragma unroll
      for (int r2 = 0; r2 < 4; r2++) {
        const int rl = i * 16 + quad * 4 + r2;
        const size_t eb = (size_t)sidP[rl] * 512;
        const float preI = aI[i][r2] + bf2f(Ep[eb + col]);
        const float preU = aU[i][r2] + bf2f(Ep[eb + 128 + col]);
        const float cv = sigmoidf_(preI) * tanhf_(preU) + bf2f(ldsF[swze(rl, col)]);
        ldsF[swze(rl, col)] = f2bf(cv);
        tch[gl][i][r2] = tanhf_(cv);
      }
  }

  // ---- o GEMM (both col-groups) + epilogue: h into stage ----
  u16* hstage = (LR == 0) ? (u16*)ldsC : (u16*)ldsA;   // both dead (same-wave col ownership)
  bf16x8 bo[2][4];
#pragma unroll
  for (int gl = 0; gl < 2; gl++)
#pragma unroll
    for (int ks = 0; ks < 4; ks++)
      bo[gl][ks] = *reinterpret_cast<const bf16x8*>(
          BohT + (size_t)(w * 32 + gl * 16 + l16) * 128 + ks * 32 + quad * 8);
  floatx4 aO[2][NI];
#pragma unroll
  for (int gl = 0; gl < 2; gl++)
#pragma unroll
    for (int i = 0; i < NI; i++) aO[gl][i] = (floatx4){0.f, 0.f, 0.f, 0.f};
#pragma unroll
  for (int ks = 0; ks < 4; ks++)
#pragma unroll
    for (int i = 0; i < NI; i++) {
      bf16x8 a = *reinterpret_cast<const bf16x8*>(&As[swz128(i * 16 + l16, ks * 4 + quad)]);
#pragma unroll
      for (int gl = 0; gl < 2; gl++)
        aO[gl][i] = __builtin_amdgcn_mfma_f32_16x16x32_bf16(a, bo[gl][ks], aO[gl][i], 0, 0, 0);
    }
#pragma unroll
  for (int gl = 0; gl < 2; gl++) {
    const int col = w * 32 + gl * 16 + l16;
#pragma unroll
    for (int i = 0; i < NI; i++)
#pragma unroll
      for (int r2 = 0; r2 < 4; r2++) {
        const int rl = i * 16 + quad * 4 + r2;
        const size_t eb = (size_t)sidP[rl] * 512;
        const float hh = sigmoidf_(aO[gl][i][r2] + bf2f(Ep[eb + 256 + col])) * tch[gl][i][r2];
        hstage[swze(rl, col)] = f2bf(hh);
      }
  }
  __syncthreads();

  // ---- dense stores: c from ldsF, h from hstage (de-swizzled chunk reads) ----
  u16* cdst = c_out + p0 * 128;
  u16* hdst = h_out + p0 * 128;
  for (int t = tid; t < PM * 16; t += 256) {
    const int r = t >> 4, c16 = t & 15;
    *reinterpret_cast<uint4*>(cdst + t * 8) = *reinterpret_cast<const uint4*>(&ldsF[swz128(r, c16)]);
    *reinterpret_cast<uint4*>(hdst + t * 8) = *reinterpret_cast<const uint4*>(&hstage[swz128(r, c16)]);
  }
}

// ---------- weight/bias prep ----------
__global__ void build_wallT(const float* __restrict__ Wix, const float* __restrict__ Wux,
                            const float* __restrict__ Wox, const float* __restrict__ Wfx,
                            u16* __restrict__ WT)
{
  int idx = blockIdx.x * 256 + threadIdx.x;   // 512*128
  int n = idx >> 7, k = idx & 127;
  int g = n >> 7, j = n & 127;
  const float* W = (g == 0) ? Wix : (g == 1) ? Wux : (g == 2) ? Wox : Wfx;
  WT[idx] = f2bf(W[k * 128 + j]);
}

__global__ void build_bsum(const float* __restrict__ b_ix, const float* __restrict__ b_ih,
                           const float* __restrict__ b_ux, const float* __restrict__ b_uh,
                           const float* __restrict__ b_ox, const float* __restrict__ b_oh,
                           const float* __restrict__ b_fx, const float* __restrict__ b_fh,
                           float* __restrict__ bsum)
{
  int n = blockIdx.x * 256 + threadIdx.x;   // 512
  int g = n >> 7, j = n & 127;
  float v = (g == 0) ? b_ix[j] + b_ih[j] : (g == 1) ? b_ux[j] + b_uh[j]
          : (g == 2) ? b_ox[j] + b_oh[j] : b_fx[j] + b_fh[j];
  bsum[n] = v;
}

__global__ void build_bt128(const float* __restrict__ W, u16* __restrict__ BT) {
  int idx = blockIdx.x * 256 + threadIdx.x;   // 128*128
  int n = idx >> 7, k = idx & 127;
  BT[idx] = f2bf(W[k * 128 + n]);
}

// ---------- output projection (4096 x 4, tiny) ----------
__global__ void out_proj(const u16* __restrict__ h_root, const float* __restrict__ W_out,
                         const float* __restrict__ b_out, float* __restrict__ out)
{
  int idx = blockIdx.x * 256 + threadIdx.x;   // 4096*4
  int n = idx >> 2, cls = idx & 3;
  float s = b_out[cls];
  for (int k = 0; k < 128; k++)
    s += bf2f(h_root[(long)n * 128 + k]) * W_out[k * 4 + cls];
  out[idx] = s;
}

extern "C" void kernel_launch(void* const* d_in, const int* in_sizes, int n_in,
                              void* d_out, int out_size, void* d_ws, size_t ws_size,
                              hipStream_t stream)
{
  const int*   sen  = (const int*)d_in[0];
  const float* emb  = (const float*)d_in[1];
  const float* W_ix = (const float*)d_in[2];  const float* b_ix = (const float*)d_in[3];
  const float* W_ih = (const float*)d_in[4];  const float* b_ih = (const float*)d_in[5];
  const float* W_fx = (const float*)d_in[6];  const float* b_fx = (const float*)d_in[7];
  const float* W_fh = (const float*)d_in[8];  const float* b_fh = (const float*)d_in[9];
  const float* W_ox = (const float*)d_in[10]; const float* b_ox = (const float*)d_in[11];
  const float* W_oh = (const float*)d_in[12]; const float* b_oh = (const float*)d_in[13];
  const float* W_ux = (const float*)d_in[14]; const float* b_ux = (const float*)d_in[15];
  const float* W_uh = (const float*)d_in[16]; const float* b_uh = (const float*)d_in[17];
  const float* W_out= (const float*)d_in[18]; const float* b_out= (const float*)d_in[19];
  float* out = (float*)d_out;

  // ---- workspace: arena A (L4/L2/L0 h+c), arena B (L3/L1 h+c), Ep, weights ----
  const size_t AH = (size_t)262144 * 128;   // u16 elems
  const size_t BH = (size_t)131072 * 128;
  const size_t EPB = (size_t)50000 * 512 * 2;
  const size_t need = 2 * AH * 2 + 2 * BH * 2 + EPB
                    + (size_t)512 * 128 * 2 + 4 * (size_t)128 * 128 * 2 + 512 * 4 + 8192;
  fprintf(stderr, "[tree_lstm] ws_size=%zu need=%zu\n", ws_size, need);
  if (ws_size < need) {
    fprintf(stderr, "[tree_lstm] INSUFFICIENT WORKSPACE — skipping launch\n");
    return;
  }
  char* ws = (char*)d_ws;
  size_t off = 0;
  auto take = [&](size_t bytes) { char* p = ws + off; off += (bytes + 255) & ~(size_t)255; return p; };
  u16* hA = (u16*)take(AH * 2);
  u16* cA = (u16*)take(AH * 2);
  u16* hB = (u16*)take(BH * 2);
  u16* cB = (u16*)take(BH * 2);
  u16* Ep = (u16*)take(EPB);
  u16* WallT = (u16*)take((size_t)512 * 128 * 2);
  u16* BihT = (u16*)take((size_t)128 * 128 * 2);
  u16* BuhT = (u16*)take((size_t)128 * 128 * 2);
  u16* BohT = (u16*)take((size_t)128 * 128 * 2);
  u16* BfhT = (u16*)take((size_t)128 * 128 * 2);
  float* bsum = (float*)take(512 * 4);

  // ---- prep ----
  build_wallT<<<256, 256, 0, stream>>>(W_ix, W_ux, W_ox, W_fx, WallT);
  build_bsum<<<2, 256, 0, stream>>>(b_ix, b_ih, b_ux, b_uh, b_ox, b_oh, b_fx, b_fh, bsum);
  build_bt128<<<64, 256, 0, stream>>>(W_ih, BihT);
  build_bt128<<<64, 256, 0, stream>>>(W_uh, BuhT);
  build_bt128<<<64, 256, 0, stream>>>(W_oh, BohT);
  build_bt128<<<64, 256, 0, stream>>>(W_fh, BfhT);
  proj_e<<<dim3(391, 4), 256, 0, stream>>>(emb, WallT, bsum, Ep);

  const long LOFF[6] = {0, 4096, 20480, 86016, 217088, 479232};

  // L4 (parents 262144, leaf children from Ep) -> A
  k_level<0, true><<<4096, 256, 0, stream>>>(sen, Ep, nullptr, nullptr,
      BfhT, BihT, BuhT, BohT, cA, hA, LOFF[4], LOFF[5]);
  // L3 (131072, ratio 2) A -> B
  k_level<1, false><<<2048, 256, 0, stream>>>(sen, Ep, hA, cA,
      BfhT, BihT, BuhT, BohT, cB, hB, LOFF[3], 0);
  // L2 (65536, ratio 2) B -> A
  k_level<1, false><<<1024, 256, 0, stream>>>(sen, Ep, hB, cB,
      BfhT, BihT, BuhT, BohT, cA, hA, LOFF[2], 0);
  // L1 (16384, ratio 4) A -> B
  k_level<2, false><<<512, 256, 0, stream>>>(sen, Ep, hA, cA,
      BfhT, BihT, BuhT, BohT, cB, hB, LOFF[1], 0);
  // L0 (4096, ratio 4) B -> A
  k_level<2, false><<<128, 256, 0, stream>>>(sen, Ep, hB, cB,
      BfhT, BihT, BuhT, BohT, cA, hA, LOFF[0], 0);

  out_proj<<<64, 256, 0, stream>>>(hA, W_out, b_out, out);
}